// Round 6
// baseline (376.424 us; speedup 1.0000x reference)
//
#include <hip/hip_runtime.h>
#include <hip/hip_bf16.h>
#include <stdint.h>

#define N_NODES 50000
#define N_EDGES 1600000
#define D_IN    512
#define D_H1    256   // 4 heads * 64 concat
#define D_OUT   64

#define NBUK    196   // coarse buckets: src>>8 (256 nodes each)
#define MAXB    9216  // per-bucket region capacity (mean 8163, +11 sigma)
#define EPB     4096  // edges per partition block
#define NPB     391   // ceil(N_EDGES / EPB)
#define SLOT    96    // per-node list stride (max degree ~58, padded to mult-4)

#define NR      50001 // rows per slice incl. zero row
#define ZROW    50000 // reserved all-zero row index (pad target)

typedef __attribute__((ext_vector_type(8))) short  short8;   // 8 bf16 = 4 VGPRs (MFMA A/B frag)
typedef __attribute__((ext_vector_type(4))) float  f32x4;    // MFMA C/D frag
typedef __attribute__((ext_vector_type(2))) float  f32x2;
typedef __attribute__((ext_vector_type(4))) unsigned int u32x4;
typedef __attribute__((ext_vector_type(2))) unsigned int u32x2;

// address-space-qualified void for the global_load_lds builtin
typedef __attribute__((address_space(1))) void GASV;
typedef __attribute__((address_space(3))) void LASV;

static __device__ __forceinline__ unsigned short f2bf(float f) {
    union { float f; unsigned int u; } c; c.f = f;
    unsigned int u = c.u;
    return (unsigned short)((u + 0x7FFFu + ((u >> 16) & 1u)) >> 16);  // RNE
}
// HW packed convert: dst.lo = bf16(a), dst.hi = bf16(b) — 1 op replaces 6.
static __device__ __forceinline__ unsigned int cvtpk(float a, float b) {
    unsigned int r;
    asm("v_cvt_pk_bf16_f32 %0, %1, %2" : "=v"(r) : "v"(a), "v"(b));
    return r;
}
static __device__ __forceinline__ unsigned short f2bf1(float f) {
    return (unsigned short)cvtpk(f, f);
}
static __device__ __forceinline__ float uasf(unsigned int u) {
    union { unsigned int u; float f; } c; c.u = u; return c.f;
}

// runtime-counted vmcnt wait (immediate-only instruction -> small switch)
static __device__ __forceinline__ void waitvm(int n) {
    switch (n) {
    case 0: asm volatile("s_waitcnt vmcnt(0)" ::: "memory"); break;
    case 1: asm volatile("s_waitcnt vmcnt(1)" ::: "memory"); break;
    case 2: asm volatile("s_waitcnt vmcnt(2)" ::: "memory"); break;
    case 3: asm volatile("s_waitcnt vmcnt(3)" ::: "memory"); break;
    case 4: asm volatile("s_waitcnt vmcnt(4)" ::: "memory"); break;
    case 5: asm volatile("s_waitcnt vmcnt(5)" ::: "memory"); break;
    case 6: asm volatile("s_waitcnt vmcnt(6)" ::: "memory"); break;
    default: asm volatile("s_waitcnt vmcnt(7)" ::: "memory"); break;
    }
    __builtin_amdgcn_sched_barrier(0);
}

// ---------------- phase 1: partition edges into 196 coarse buckets ----------------

__global__ __launch_bounds__(256) void part_kernel(const int* __restrict__ src,
                                                   const int* __restrict__ dst,
                                                   int* __restrict__ gcnt,
                                                   unsigned int* __restrict__ gbuk) {
    __shared__ int hist[NBUK];
    __shared__ int lofs[NBUK];          // exclusive offsets in sorted[]
    __shared__ int gbase[NBUK];         // this block's reservation in bucket region
    __shared__ int sbuf[256];
    __shared__ unsigned int sorted[EPB];
    __shared__ unsigned char bid[EPB];

    const int t  = threadIdx.x;
    const int e0 = blockIdx.x * EPB;
    int ec = N_EDGES - e0; if (ec > EPB) ec = EPB;

    for (int i = t; i < NBUK; i += 256) hist[i] = 0;
    __syncthreads();

    unsigned int rec[16];
    int bb[16], idx[16];
#pragma unroll
    for (int j = 0; j < 16; ++j) {
        int i = j * 256 + t;
        if (i < ec) {
            int s = src[e0 + i], d = dst[e0 + i];
            int b = s >> 8;
            rec[j] = ((unsigned int)(s & 255) << 16) | (unsigned int)d;
            bb[j]  = b;
            idx[j] = atomicAdd(&hist[b], 1);
        } else bb[j] = -1;
    }
    __syncthreads();

    // inclusive scan of hist over 256 slots (entries >= NBUK are 0)
    int v = (t < NBUK) ? hist[t] : 0;
    sbuf[t] = v;
    __syncthreads();
#pragma unroll
    for (int off = 1; off < 256; off <<= 1) {
        int x = (t >= off) ? sbuf[t - off] : 0;
        __syncthreads();
        sbuf[t] += x;
        __syncthreads();
    }
    if (t < NBUK) {
        lofs[t]  = sbuf[t] - v;                 // exclusive
        gbase[t] = atomicAdd(&gcnt[t], v);      // one global atomic per bucket per block
    }
    __syncthreads();

#pragma unroll
    for (int j = 0; j < 16; ++j) {
        if (bb[j] >= 0) {
            int p = lofs[bb[j]] + idx[j];
            sorted[p] = rec[j];
            bid[p] = (unsigned char)bb[j];
        }
    }
    __syncthreads();

    for (int i = t; i < ec; i += 256) {
        int b = bid[i];
        int p = gbase[b] + (i - lofs[b]);
        gbuk[(size_t)b * MAXB + p] = sorted[i];
    }
}

// ---------------- phase 2: per-bucket LDS counting sort -> per-node padded lists ----------------

__global__ __launch_bounds__(256) void sort_kernel(const int* __restrict__ gcnt,
                                                   const unsigned int* __restrict__ gbuk,
                                                   unsigned short* __restrict__ sdst,
                                                   int* __restrict__ deg) {
    __shared__ int hist[256];
    __shared__ int nofs[256];           // exclusive offsets, used as running cursors
    __shared__ int sbuf[256];
    __shared__ unsigned short list[MAXB];

    const int t = threadIdx.x;
    const int b = blockIdx.x;
    const int cnt = gcnt[b];
    const unsigned int* buk = gbuk + (size_t)b * MAXB;

    hist[t] = 0;
    __syncthreads();
    for (int i = t; i < cnt; i += 256)
        atomicAdd(&hist[buk[i] >> 16], 1);
    __syncthreads();

    int v = hist[t];
    sbuf[t] = v;
    __syncthreads();
#pragma unroll
    for (int off = 1; off < 256; off <<= 1) {
        int x = (t >= off) ? sbuf[t - off] : 0;
        __syncthreads();
        sbuf[t] += x;
        __syncthreads();
    }
    nofs[t] = sbuf[t] - v;              // exclusive
    const int n = b * 256 + t;
    if (n < N_NODES) deg[n] = v;
    __syncthreads();

    for (int i = t; i < cnt; i += 256) {
        unsigned int r = buk[i];
        int p = atomicAdd(&nofs[r >> 16], 1);
        list[p] = (unsigned short)(r & 0xffffu);
    }
    __syncthreads();

    // cooperative coalesced writeout: 8 lanes per node, pad to mult-4 with ZROW
    for (int base = 0; base < 256; base += 32) {
        int node = base + (t >> 3);
        int l8   = t & 7;
        int vv   = hist[node];
        int beg  = nofs[node] - vv;     // nofs is now inclusive end
        int n2   = b * 256 + node;
        if (n2 < N_NODES) {
            int words = ((vv + 3) & ~3) >> 1;
            unsigned int* out32 = (unsigned int*)(sdst + (size_t)n2 * SLOT);
            for (int j2 = l8; j2 < words; j2 += 8) {
                unsigned int lo = (2 * j2     < vv) ? list[beg + 2 * j2]     : (unsigned int)ZROW;
                unsigned int hi = (2 * j2 + 1 < vv) ? list[beg + 2 * j2 + 1] : (unsigned int)ZROW;
                out32[j2] = lo | (hi << 16);
            }
        }
    }
}

// ---------------- weight repack + zero-row init ----------------

__global__ void convw_kernel(const float* __restrict__ W1, const float* __restrict__ W2,
                             unsigned short* __restrict__ Bt1, unsigned short* __restrict__ Bt2,
                             unsigned short* __restrict__ t1, unsigned short* __restrict__ t2) {
    int i = blockIdx.x * 256 + threadIdx.x;
    if (i < 4 * 512 * 64) {                 // W1[h][k][j] -> Bt1[(h*64+j)][k]
        int h = i >> 15;
        int k = (i >> 6) & 511;
        int j = i & 63;
        Bt1[(h * 64 + j) * 512 + k] = f2bf(W1[i]);
    } else if (i < 4 * 512 * 64 + 256 * 64) {
        int r = i - 4 * 512 * 64;           // W2[k][n] -> Bt2[n][k]
        int k = r >> 6;
        int n = r & 63;
        Bt2[n * 256 + k] = f2bf(W2[r]);
    } else {
        int r = i - (4 * 512 * 64 + 256 * 64);
        if (r < 8 * 32) {                   // zero row of each t1 slice
            t1[(size_t)(r >> 5) * ((size_t)NR * 32) + (size_t)ZROW * 32 + (r & 31)] = 0;
        } else if (r < 8 * 32 + 2 * 32) {   // zero row of each t2 slice
            int q = r - 8 * 32;
            t2[(size_t)(q >> 5) * ((size_t)NR * 32) + (size_t)ZROW * 32 + (q & 31)] = 0;
        }
    }
}

// ---------------- GEMM1: t1s[8][NR][32] = slice-major( X[M][512] @ Bt1[256][512]^T ) ----------------
// BM=128, BN=256 (A read once), block=512 (8 waves 2x4), wave tile 64x64, BK=32.

__global__ __launch_bounds__(512) void gemm1_kernel(const float* __restrict__ A,
                                                    const unsigned short* __restrict__ Bt,
                                                    unsigned short* __restrict__ C) {
    constexpr int BM = 128, BK = 32, LDK = 40, K = D_IN, M = N_NODES;
    __shared__ unsigned short As[BM * LDK];   // 10.0 KB
    __shared__ unsigned short Bs[256 * LDK];  // 20.0 KB

    const int tid  = threadIdx.x;
    const int lane = tid & 63;
    const int w    = tid >> 6;
    const int wm   = (w >> 2) * 64;
    const int wn   = (w & 3) * 64;
    const int quad = lane >> 4;
    const int l15  = lane & 15;
    const int bm   = blockIdx.x;

    f32x4 acc[4][4];
#pragma unroll
    for (int mi = 0; mi < 4; ++mi)
#pragma unroll
        for (int ni = 0; ni < 4; ++ni)
            acc[mi][ni] = (f32x4){0.f, 0.f, 0.f, 0.f};

    const int r0 = tid >> 2;      // 0..127
    const int f8 = tid & 3;       // 8-elem chunk within a 32-col row

    for (int k0 = 0; k0 < K; k0 += BK) {
        {   // stage A (128 x 32 fp32 -> bf16), 8 floats per thread, HW pack-convert
            int grow = bm * BM + r0;
            if (grow >= M) grow = M - 1;
            const float* ap = A + (size_t)grow * K + k0 + f8 * 8;
            f32x4 v0 = *(const f32x4*)ap;
            f32x4 v1 = *(const f32x4*)(ap + 4);
            u32x4 pk;
            pk[0] = cvtpk(v0[0], v0[1]);
            pk[1] = cvtpk(v0[2], v0[3]);
            pk[2] = cvtpk(v1[0], v1[1]);
            pk[3] = cvtpk(v1[2], v1[3]);
            *(u32x4*)&As[r0 * LDK + f8 * 8] = pk;
        }
        {   // stage B (256 x 32 bf16), two u32x4 per thread
#pragma unroll
            for (int p = 0; p < 2; ++p) {
                int row = p * 128 + r0;
                u32x4 v = *(const u32x4*)(Bt + (size_t)row * K + k0 + f8 * 8);
                *(u32x4*)&Bs[row * LDK + f8 * 8] = v;
            }
        }
        __syncthreads();

        short8 af[4], bfr[4];
#pragma unroll
        for (int mi = 0; mi < 4; ++mi)
            af[mi] = *(const short8*)&As[(wm + mi * 16 + l15) * LDK + quad * 8];
#pragma unroll
        for (int ni = 0; ni < 4; ++ni)
            bfr[ni] = *(const short8*)&Bs[(wn + ni * 16 + l15) * LDK + quad * 8];
#pragma unroll
        for (int mi = 0; mi < 4; ++mi)
#pragma unroll
            for (int ni = 0; ni < 4; ++ni)
                acc[mi][ni] = __builtin_amdgcn_mfma_f32_16x16x32_bf16(af[mi], bfr[ni], acc[mi][ni], 0, 0, 0);
        __syncthreads();
    }

    // epilogue: slice-major store  t1s[col>>5][row][col&31]
#pragma unroll
    for (int mi = 0; mi < 4; ++mi) {
        int row0 = bm * BM + wm + mi * 16 + quad * 4;
#pragma unroll
        for (int ni = 0; ni < 4; ++ni) {
            int col = wn + ni * 16 + l15;
            unsigned short* cp = C + (size_t)(col >> 5) * ((size_t)NR * 32) + (col & 31);
#pragma unroll
            for (int r = 0; r < 4; ++r) {
                int row = row0 + r;
                if (row < M) cp[(size_t)row * 32] = f2bf1(acc[mi][ni][r]);
            }
        }
    }
}

// ---------------- GEMM2: t2s[2][NR][32] = slice-major( h[M][256](bf16) @ Bt2[64][256]^T ) ----------------

__global__ __launch_bounds__(256) void gemm2_kernel(const unsigned short* __restrict__ A,
                                                    const unsigned short* __restrict__ Bt,
                                                    unsigned short* __restrict__ C) {
    constexpr int BM = 64, BK = 32, LDK = 40, K = D_H1, M = N_NODES;
    __shared__ unsigned short As[BM * LDK];
    __shared__ unsigned short Bs[64 * LDK];

    const int tid  = threadIdx.x;
    const int lane = tid & 63;
    const int w    = tid >> 6;
    const int wm   = (w >> 1) * 32;
    const int wn   = (w & 1) * 32;
    const int quad = lane >> 4;
    const int l15  = lane & 15;
    const int bm   = blockIdx.x;

    f32x4 acc[2][2];
#pragma unroll
    for (int mi = 0; mi < 2; ++mi)
#pragma unroll
        for (int ni = 0; ni < 2; ++ni)
            acc[mi][ni] = (f32x4){0.f, 0.f, 0.f, 0.f};

    for (int k0 = 0; k0 < K; k0 += BK) {
        {
            int f8 = tid & 3;
            int r0 = tid >> 2;
            int grow = bm * BM + r0;
            if (grow >= M) grow = M - 1;
            u32x4 v = *(const u32x4*)(A + (size_t)grow * K + k0 + f8 * 8);
            *(u32x4*)&As[r0 * LDK + f8 * 8] = v;
        }
        {
            int f8 = tid & 3;
            int r0 = tid >> 2;
            u32x4 v = *(const u32x4*)(Bt + (size_t)r0 * K + k0 + f8 * 8);
            *(u32x4*)&Bs[r0 * LDK + f8 * 8] = v;
        }
        __syncthreads();

        short8 af[2], bfr[2];
#pragma unroll
        for (int mi = 0; mi < 2; ++mi)
            af[mi] = *(const short8*)&As[(wm + mi * 16 + l15) * LDK + quad * 8];
#pragma unroll
        for (int ni = 0; ni < 2; ++ni)
            bfr[ni] = *(const short8*)&Bs[(wn + ni * 16 + l15) * LDK + quad * 8];
#pragma unroll
        for (int mi = 0; mi < 2; ++mi)
#pragma unroll
            for (int ni = 0; ni < 2; ++ni)
                acc[mi][ni] = __builtin_amdgcn_mfma_f32_16x16x32_bf16(af[mi], bfr[ni], acc[mi][ni], 0, 0, 0);
        __syncthreads();
    }

#pragma unroll
    for (int mi = 0; mi < 2; ++mi) {
        int row0 = bm * BM + wm + mi * 16 + quad * 4;
#pragma unroll
        for (int ni = 0; ni < 2; ++ni) {
            int col = wn + ni * 16 + l15;
            unsigned short* cp = C + (size_t)(col >> 5) * ((size_t)NR * 32) + (col & 31);
#pragma unroll
            for (int r = 0; r < 4; ++r) {
                int row = row0 + r;
                if (row < M) cp[(size_t)row * 32] = f2bf1(acc[mi][ni][r]);
            }
        }
    }
}

// ---------------- aggregation: XCD-pinned slices + mixed-size pipelined DMA gathers ----------------
// Gather is bound by a ~0.2 64B-request/cy/CU wall (R0/R2/R4 converge on it): requests are
// the roofline currency. Lists pad to mult-4 (avg 33.5 lines/node vs 43 at mult-16).
// Decomposition in PADDED-QUAD units (R5 bugfix): nq4 = pad4(deg)/4; nb = nq4>>2 full
// 16-row (1KB) DMAs -- legally covering ZROW-padded entries -- plus nt = nq4&3 size-4
// (4-row) DMAs. nt <= 3 always; r16[4] covers deg <= 64.
// Cross-node vmcnt pipeline: N = n(j+1) + 1(store), never a full drain mid-loop.

#define AGG_ISSUE(J, B, NJ)                                                             \
    int NJ;                                                                             \
    {                                                                                   \
        const int nq4 = (end##J + 3) >> 2;                                              \
        const int nb  = nq4 >> 2;                                                       \
        const int nt  = nq4 & 3;                                                        \
        int r16[4], r4s[3];                                                             \
        _Pragma("unroll")                                                               \
        for (int k = 0; k < 4; ++k)                                                     \
            r16[k] = __shfl(elv##J, ((k << 4) + (lane >> 2)) & 63);                     \
        _Pragma("unroll")                                                               \
        for (int tt = 0; tt < 3; ++tt)                                                  \
            r4s[tt] = __shfl(elv##J, ((nb << 4) + (tt << 2) + (lane >> 4)) & 63);       \
        for (int k = 0; k < nb; ++k)                                                    \
            __builtin_amdgcn_global_load_lds(                                           \
                (GASV*)(tb32 + ((unsigned)r16[k] << 4) + ((lane & 3) << 2)),            \
                (LASV*)(&ring[w][B][k << 8]), 16, 0, 0);                                \
        for (int tt = 0; tt < nt; ++tt)                                                 \
            __builtin_amdgcn_global_load_lds(                                           \
                (GASV*)(tb32 + ((unsigned)r4s[tt] << 4) + (lane & 15)),                 \
                (LASV*)(&ring[w][B][(nb << 8) + (tt << 6)]), 4, 0, 0);                  \
        NJ = nb + nt;                                                                   \
    }

#define AGG_CONSUME(J, B)                                                               \
    {                                                                                   \
        const int nq = (end##J + 3) >> 2;                                               \
        f32x2 Acc = {0.f, 0.f};                                                         \
        const unsigned int* rb = &ring[w][B][lane];                                     \
        for (int q = 0; q < nq; ++q) {                                                  \
            unsigned int v = rb[q << 6];                                                \
            Acc.x += uasf(v << 16);                                                     \
            Acc.y += uasf(v & 0xffff0000u);                                             \
        }                                                                               \
        f32x2 Bv;                                                                       \
        Bv.x = __shfl_xor(Acc.x, 16); Bv.y = __shfl_xor(Acc.y, 16); Acc += Bv;          \
        Bv.x = __shfl_xor(Acc.x, 32); Bv.y = __shfl_xor(Acc.y, 32); Acc += Bv;          \
        if (lane < 16) {                                                                \
            float iv = (end##J > 0) ? (1.0f / (float)end##J) : 0.f;                     \
            float m0 = Acc.x * iv, m1 = Acc.y * iv;                                     \
            if (ELU) {                                                                  \
                m0 = (m0 > 0.f) ? m0 : (__expf(m0) - 1.f);                              \
                m1 = (m1 > 0.f) ? m1 : (__expf(m1) - 1.f);                              \
                *(unsigned int*)&hout[(size_t)(s0 + J) * D_H1 + slice * 32 + (lane & 15) * 2] = cvtpk(m0, m1); \
            } else {                                                                    \
                f32x2 r; r.x = m0; r.y = m1;                                            \
                *(f32x2*)(fout + (size_t)(s0 + J) * D_OUT + slice * 32 + (lane & 15) * 2) = r; \
            }                                                                           \
        }                                                                               \
        __builtin_amdgcn_sched_barrier(0);                                              \
    }

template<int LOGS, bool ELU>
__global__ __launch_bounds__(256) void agg_kernel(const unsigned short* __restrict__ t,
                                                  const int* __restrict__ deg,
                                                  const unsigned short* __restrict__ sdst,
                                                  unsigned short* __restrict__ hout,
                                                  float* __restrict__ fout) {
    __shared__ __align__(16) unsigned int ring[4][2][1024];   // 32 KB (<=64 rows/slot)
    const int bi    = blockIdx.x;
    const int slice = bi & ((1 << LOGS) - 1);
    const int g     = bi >> LOGS;
    const int w     = __builtin_amdgcn_readfirstlane(threadIdx.x >> 6);
    const int lane  = threadIdx.x & 63;
    const unsigned int* tb32 = (const unsigned int*)t + (size_t)slice * ((size_t)NR * 16);

    const int s0 = g * 16 + w * 4;
    const int end0 = deg[s0 + 0], end1 = deg[s0 + 1], end2 = deg[s0 + 2], end3 = deg[s0 + 3];
    const int elv0 = sdst[(size_t)(s0 + 0) * SLOT + lane];
    const int elv1 = sdst[(size_t)(s0 + 1) * SLOT + lane];
    const int elv2 = sdst[(size_t)(s0 + 2) * SLOT + lane];
    const int elv3 = sdst[(size_t)(s0 + 3) * SLOT + lane];

    AGG_ISSUE(0, 0, n0i);
    AGG_ISSUE(1, 1, n1i); waitvm(n1i);        // node0 loads landed (n1 newest stay in flight)
    AGG_CONSUME(0, 0);                        // ends with 1 global store
    AGG_ISSUE(2, 0, n2i); waitvm(n2i + 1);    // +1: store(0) may still be outstanding
    AGG_CONSUME(1, 1);
    AGG_ISSUE(3, 1, n3i); waitvm(n3i + 1);
    AGG_CONSUME(2, 0);
    waitvm(1);                                // node3 loads done (store(2) may remain)
    AGG_CONSUME(3, 1);
}

// ---------------- launch ----------------

extern "C" void kernel_launch(void* const* d_in, const int* in_sizes, int n_in,
                              void* d_out, int out_size, void* d_ws, size_t ws_size,
                              hipStream_t stream) {
    const float* X  = (const float*)d_in[0];
    const int*   ei = (const int*)d_in[1];
    const float* W1 = (const float*)d_in[2];
    const float* W2 = (const float*)d_in[3];
    const int* src = ei;             // edge_index[0] = segment ids
    const int* dst = ei + N_EDGES;   // edge_index[1] = gathered neighbors

    char* ws = (char*)d_ws;
    size_t off = 0;
    auto alloc = [&](size_t bytes) {
        off = (off + 255) & ~(size_t)255;
        void* p = ws + off;
        off += bytes;
        return p;
    };
    int*          gcnt = (int*)alloc((size_t)NBUK * 4);
    unsigned int* gbuk = (unsigned int*)alloc((size_t)NBUK * MAXB * 4);
    unsigned short* sdst = (unsigned short*)alloc(((size_t)N_NODES * SLOT + 64) * 2);
    int*          deg  = (int*)alloc((size_t)N_NODES * 4);
    unsigned short* Bt1 = (unsigned short*)alloc((size_t)D_H1 * D_IN * 2);
    unsigned short* Bt2 = (unsigned short*)alloc((size_t)D_OUT * D_H1 * 2);
    unsigned short* t1  = (unsigned short*)alloc((size_t)8 * NR * 32 * 2);
    unsigned short* h   = (unsigned short*)alloc((size_t)N_NODES * D_H1 * 2);
    unsigned short* t2  = (unsigned short*)alloc((size_t)2 * NR * 32 * 2);

    hipMemsetAsync(gcnt, 0, (size_t)NBUK * 4, stream);

    part_kernel<<<NPB, 256, 0, stream>>>(src, dst, gcnt, gbuk);
    sort_kernel<<<NBUK, 256, 0, stream>>>(gcnt, gbuk, sdst, deg);
    convw_kernel<<<(4 * 512 * 64 + 256 * 64 + 8 * 32 + 2 * 32 + 255) / 256, 256, 0, stream>>>(
        W1, W2, Bt1, Bt2, t1, t2);

    gemm1_kernel<<<(N_NODES + 127) / 128, 512, 0, stream>>>(X, Bt1, t1);
    agg_kernel<3, true><<<(N_NODES / 16) * 8, 256, 0, stream>>>(t1, deg, sdst, h, nullptr);
    gemm2_kernel<<<(N_NODES + 63) / 64, 256, 0, stream>>>(h, Bt2, t2);
    agg_kernel<1, false><<<(N_NODES / 16) * 2, 256, 0, stream>>>(t2, deg, sdst, nullptr, (float*)d_out);
}

// Round 7
// 370.452 us; speedup vs baseline: 1.0161x; 1.0161x over previous
//
#include <hip/hip_runtime.h>
#include <hip/hip_bf16.h>
#include <stdint.h>

#define N_NODES 50000
#define N_EDGES 1600000
#define D_IN    512
#define D_H1    256   // 4 heads * 64 concat
#define D_OUT   64

#define NBUK    196   // coarse buckets: src>>8 (256 nodes each)
#define MAXB    9216  // per-bucket region capacity (mean 8163, +11 sigma)
#define EPB     4096  // edges per partition block
#define NPB     391   // ceil(N_EDGES / EPB)
#define SLOT    96    // per-node list stride (max degree ~58, padded to mult-4)

#define NR      50001 // rows per slice incl. zero row
#define ZROW    50000 // reserved all-zero row index (pad target)

typedef __attribute__((ext_vector_type(8))) short  short8;   // 8 bf16 = 4 VGPRs (MFMA A/B frag)
typedef __attribute__((ext_vector_type(4))) float  f32x4;    // MFMA C/D frag
typedef __attribute__((ext_vector_type(2))) float  f32x2;
typedef __attribute__((ext_vector_type(4))) unsigned int u32x4;
typedef __attribute__((ext_vector_type(2))) unsigned int u32x2;

// address-space-qualified void for the global_load_lds builtin
typedef __attribute__((address_space(1))) void GASV;
typedef __attribute__((address_space(3))) void LASV;

static __device__ __forceinline__ unsigned short f2bf(float f) {
    union { float f; unsigned int u; } c; c.f = f;
    unsigned int u = c.u;
    return (unsigned short)((u + 0x7FFFu + ((u >> 16) & 1u)) >> 16);  // RNE
}
// HW packed convert: dst.lo = bf16(a), dst.hi = bf16(b) — 1 op replaces 6.
static __device__ __forceinline__ unsigned int cvtpk(float a, float b) {
    unsigned int r;
    asm("v_cvt_pk_bf16_f32 %0, %1, %2" : "=v"(r) : "v"(a), "v"(b));
    return r;
}
static __device__ __forceinline__ unsigned short f2bf1(float f) {
    return (unsigned short)cvtpk(f, f);
}
static __device__ __forceinline__ float uasf(unsigned int u) {
    union { unsigned int u; float f; } c; c.u = u; return c.f;
}

// runtime-counted vmcnt wait (immediate-only instruction -> small switch)
static __device__ __forceinline__ void waitvm(int n) {
    switch (n) {
    case 0: asm volatile("s_waitcnt vmcnt(0)" ::: "memory"); break;
    case 1: asm volatile("s_waitcnt vmcnt(1)" ::: "memory"); break;
    case 2: asm volatile("s_waitcnt vmcnt(2)" ::: "memory"); break;
    case 3: asm volatile("s_waitcnt vmcnt(3)" ::: "memory"); break;
    case 4: asm volatile("s_waitcnt vmcnt(4)" ::: "memory"); break;
    case 5: asm volatile("s_waitcnt vmcnt(5)" ::: "memory"); break;
    case 6: asm volatile("s_waitcnt vmcnt(6)" ::: "memory"); break;
    default: asm volatile("s_waitcnt vmcnt(7)" ::: "memory"); break;
    }
    __builtin_amdgcn_sched_barrier(0);
}

// ---------------- phase 1: partition edges into 196 coarse buckets ----------------

__global__ __launch_bounds__(256) void part_kernel(const int* __restrict__ src,
                                                   const int* __restrict__ dst,
                                                   int* __restrict__ gcnt,
                                                   unsigned int* __restrict__ gbuk) {
    __shared__ int hist[NBUK];
    __shared__ int lofs[NBUK];          // exclusive offsets in sorted[]
    __shared__ int gbase[NBUK];         // this block's reservation in bucket region
    __shared__ int sbuf[256];
    __shared__ unsigned int sorted[EPB];
    __shared__ unsigned char bid[EPB];

    const int t  = threadIdx.x;
    const int e0 = blockIdx.x * EPB;
    int ec = N_EDGES - e0; if (ec > EPB) ec = EPB;

    for (int i = t; i < NBUK; i += 256) hist[i] = 0;
    __syncthreads();

    unsigned int rec[16];
    int bb[16], idx[16];
#pragma unroll
    for (int j = 0; j < 16; ++j) {
        int i = j * 256 + t;
        if (i < ec) {
            int s = src[e0 + i], d = dst[e0 + i];
            int b = s >> 8;
            rec[j] = ((unsigned int)(s & 255) << 16) | (unsigned int)d;
            bb[j]  = b;
            idx[j] = atomicAdd(&hist[b], 1);
        } else bb[j] = -1;
    }
    __syncthreads();

    // inclusive scan of hist over 256 slots (entries >= NBUK are 0)
    int v = (t < NBUK) ? hist[t] : 0;
    sbuf[t] = v;
    __syncthreads();
#pragma unroll
    for (int off = 1; off < 256; off <<= 1) {
        int x = (t >= off) ? sbuf[t - off] : 0;
        __syncthreads();
        sbuf[t] += x;
        __syncthreads();
    }
    if (t < NBUK) {
        lofs[t]  = sbuf[t] - v;                 // exclusive
        gbase[t] = atomicAdd(&gcnt[t], v);      // one global atomic per bucket per block
    }
    __syncthreads();

#pragma unroll
    for (int j = 0; j < 16; ++j) {
        if (bb[j] >= 0) {
            int p = lofs[bb[j]] + idx[j];
            sorted[p] = rec[j];
            bid[p] = (unsigned char)bb[j];
        }
    }
    __syncthreads();

    for (int i = t; i < ec; i += 256) {
        int b = bid[i];
        int p = gbase[b] + (i - lofs[b]);
        gbuk[(size_t)b * MAXB + p] = sorted[i];
    }
}

// ---------------- phase 2: per-bucket LDS counting sort -> per-node padded lists ----------------

__global__ __launch_bounds__(256) void sort_kernel(const int* __restrict__ gcnt,
                                                   const unsigned int* __restrict__ gbuk,
                                                   unsigned short* __restrict__ sdst,
                                                   int* __restrict__ deg) {
    __shared__ int hist[256];
    __shared__ int nofs[256];           // exclusive offsets, used as running cursors
    __shared__ int sbuf[256];
    __shared__ unsigned short list[MAXB];

    const int t = threadIdx.x;
    const int b = blockIdx.x;
    const int cnt = gcnt[b];
    const unsigned int* buk = gbuk + (size_t)b * MAXB;

    hist[t] = 0;
    __syncthreads();
    for (int i = t; i < cnt; i += 256)
        atomicAdd(&hist[buk[i] >> 16], 1);
    __syncthreads();

    int v = hist[t];
    sbuf[t] = v;
    __syncthreads();
#pragma unroll
    for (int off = 1; off < 256; off <<= 1) {
        int x = (t >= off) ? sbuf[t - off] : 0;
        __syncthreads();
        sbuf[t] += x;
        __syncthreads();
    }
    nofs[t] = sbuf[t] - v;              // exclusive
    const int n = b * 256 + t;
    if (n < N_NODES) deg[n] = v;
    __syncthreads();

    for (int i = t; i < cnt; i += 256) {
        unsigned int r = buk[i];
        int p = atomicAdd(&nofs[r >> 16], 1);
        list[p] = (unsigned short)(r & 0xffffu);
    }
    __syncthreads();

    // cooperative coalesced writeout: 8 lanes per node, pad to mult-4 with ZROW
    for (int base = 0; base < 256; base += 32) {
        int node = base + (t >> 3);
        int l8   = t & 7;
        int vv   = hist[node];
        int beg  = nofs[node] - vv;     // nofs is now inclusive end
        int n2   = b * 256 + node;
        if (n2 < N_NODES) {
            int words = ((vv + 3) & ~3) >> 1;
            unsigned int* out32 = (unsigned int*)(sdst + (size_t)n2 * SLOT);
            for (int j2 = l8; j2 < words; j2 += 8) {
                unsigned int lo = (2 * j2     < vv) ? list[beg + 2 * j2]     : (unsigned int)ZROW;
                unsigned int hi = (2 * j2 + 1 < vv) ? list[beg + 2 * j2 + 1] : (unsigned int)ZROW;
                out32[j2] = lo | (hi << 16);
            }
        }
    }
}

// ---------------- weight repack + zero-row init ----------------

__global__ void convw_kernel(const float* __restrict__ W1, const float* __restrict__ W2,
                             unsigned short* __restrict__ Bt1, unsigned short* __restrict__ Bt2,
                             unsigned short* __restrict__ t1, unsigned short* __restrict__ t2) {
    int i = blockIdx.x * 256 + threadIdx.x;
    if (i < 4 * 512 * 64) {                 // W1[h][k][j] -> Bt1[(h*64+j)][k]
        int h = i >> 15;
        int k = (i >> 6) & 511;
        int j = i & 63;
        Bt1[(h * 64 + j) * 512 + k] = f2bf(W1[i]);
    } else if (i < 4 * 512 * 64 + 256 * 64) {
        int r = i - 4 * 512 * 64;           // W2[k][n] -> Bt2[n][k]
        int k = r >> 6;
        int n = r & 63;
        Bt2[n * 256 + k] = f2bf(W2[r]);
    } else {
        int r = i - (4 * 512 * 64 + 256 * 64);
        if (r < 8 * 32) {                   // zero row of each t1 slice
            t1[(size_t)(r >> 5) * ((size_t)NR * 32) + (size_t)ZROW * 32 + (r & 31)] = 0;
        } else if (r < 8 * 32 + 2 * 32) {   // zero row of each t2 slice
            int q = r - 8 * 32;
            t2[(size_t)(q >> 5) * ((size_t)NR * 32) + (size_t)ZROW * 32 + (q & 31)] = 0;
        }
    }
}

// ---------------- GEMM1: t1s[8][NR][32] = slice-major( X[M][512] @ Bt1[256][512]^T ) ----------------
// BM=128, BN=256 (A read once), block=512 (8 waves 2x4), wave tile 64x64, BK=32.

__global__ __launch_bounds__(512) void gemm1_kernel(const float* __restrict__ A,
                                                    const unsigned short* __restrict__ Bt,
                                                    unsigned short* __restrict__ C) {
    constexpr int BM = 128, BK = 32, LDK = 40, K = D_IN, M = N_NODES;
    __shared__ unsigned short As[BM * LDK];   // 10.0 KB
    __shared__ unsigned short Bs[256 * LDK];  // 20.0 KB

    const int tid  = threadIdx.x;
    const int lane = tid & 63;
    const int w    = tid >> 6;
    const int wm   = (w >> 2) * 64;
    const int wn   = (w & 3) * 64;
    const int quad = lane >> 4;
    const int l15  = lane & 15;
    const int bm   = blockIdx.x;

    f32x4 acc[4][4];
#pragma unroll
    for (int mi = 0; mi < 4; ++mi)
#pragma unroll
        for (int ni = 0; ni < 4; ++ni)
            acc[mi][ni] = (f32x4){0.f, 0.f, 0.f, 0.f};

    const int r0 = tid >> 2;      // 0..127
    const int f8 = tid & 3;       // 8-elem chunk within a 32-col row

    for (int k0 = 0; k0 < K; k0 += BK) {
        {   // stage A (128 x 32 fp32 -> bf16), 8 floats per thread, HW pack-convert
            int grow = bm * BM + r0;
            if (grow >= M) grow = M - 1;
            const float* ap = A + (size_t)grow * K + k0 + f8 * 8;
            f32x4 v0 = *(const f32x4*)ap;
            f32x4 v1 = *(const f32x4*)(ap + 4);
            u32x4 pk;
            pk[0] = cvtpk(v0[0], v0[1]);
            pk[1] = cvtpk(v0[2], v0[3]);
            pk[2] = cvtpk(v1[0], v1[1]);
            pk[3] = cvtpk(v1[2], v1[3]);
            *(u32x4*)&As[r0 * LDK + f8 * 8] = pk;
        }
        {   // stage B (256 x 32 bf16), two u32x4 per thread
#pragma unroll
            for (int p = 0; p < 2; ++p) {
                int row = p * 128 + r0;
                u32x4 v = *(const u32x4*)(Bt + (size_t)row * K + k0 + f8 * 8);
                *(u32x4*)&Bs[row * LDK + f8 * 8] = v;
            }
        }
        __syncthreads();

        short8 af[4], bfr[4];
#pragma unroll
        for (int mi = 0; mi < 4; ++mi)
            af[mi] = *(const short8*)&As[(wm + mi * 16 + l15) * LDK + quad * 8];
#pragma unroll
        for (int ni = 0; ni < 4; ++ni)
            bfr[ni] = *(const short8*)&Bs[(wn + ni * 16 + l15) * LDK + quad * 8];
#pragma unroll
        for (int mi = 0; mi < 4; ++mi)
#pragma unroll
            for (int ni = 0; ni < 4; ++ni)
                acc[mi][ni] = __builtin_amdgcn_mfma_f32_16x16x32_bf16(af[mi], bfr[ni], acc[mi][ni], 0, 0, 0);
        __syncthreads();
    }

    // epilogue: slice-major store  t1s[col>>5][row][col&31]
#pragma unroll
    for (int mi = 0; mi < 4; ++mi) {
        int row0 = bm * BM + wm + mi * 16 + quad * 4;
#pragma unroll
        for (int ni = 0; ni < 4; ++ni) {
            int col = wn + ni * 16 + l15;
            unsigned short* cp = C + (size_t)(col >> 5) * ((size_t)NR * 32) + (col & 31);
#pragma unroll
            for (int r = 0; r < 4; ++r) {
                int row = row0 + r;
                if (row < M) cp[(size_t)row * 32] = f2bf1(acc[mi][ni][r]);
            }
        }
    }
}

// ---------------- GEMM2: t2s[2][NR][32] = slice-major( h[M][256](bf16) @ Bt2[64][256]^T ) ----------------

__global__ __launch_bounds__(256) void gemm2_kernel(const unsigned short* __restrict__ A,
                                                    const unsigned short* __restrict__ Bt,
                                                    unsigned short* __restrict__ C) {
    constexpr int BM = 64, BK = 32, LDK = 40, K = D_H1, M = N_NODES;
    __shared__ unsigned short As[BM * LDK];
    __shared__ unsigned short Bs[64 * LDK];

    const int tid  = threadIdx.x;
    const int lane = tid & 63;
    const int w    = tid >> 6;
    const int wm   = (w >> 1) * 32;
    const int wn   = (w & 1) * 32;
    const int quad = lane >> 4;
    const int l15  = lane & 15;
    const int bm   = blockIdx.x;

    f32x4 acc[2][2];
#pragma unroll
    for (int mi = 0; mi < 2; ++mi)
#pragma unroll
        for (int ni = 0; ni < 2; ++ni)
            acc[mi][ni] = (f32x4){0.f, 0.f, 0.f, 0.f};

    for (int k0 = 0; k0 < K; k0 += BK) {
        {
            int f8 = tid & 3;
            int r0 = tid >> 2;
            int grow = bm * BM + r0;
            if (grow >= M) grow = M - 1;
            u32x4 v = *(const u32x4*)(A + (size_t)grow * K + k0 + f8 * 8);
            *(u32x4*)&As[r0 * LDK + f8 * 8] = v;
        }
        {
            int f8 = tid & 3;
            int r0 = tid >> 2;
            u32x4 v = *(const u32x4*)(Bt + (size_t)r0 * K + k0 + f8 * 8);
            *(u32x4*)&Bs[r0 * LDK + f8 * 8] = v;
        }
        __syncthreads();

        short8 af[2], bfr[2];
#pragma unroll
        for (int mi = 0; mi < 2; ++mi)
            af[mi] = *(const short8*)&As[(wm + mi * 16 + l15) * LDK + quad * 8];
#pragma unroll
        for (int ni = 0; ni < 2; ++ni)
            bfr[ni] = *(const short8*)&Bs[(wn + ni * 16 + l15) * LDK + quad * 8];
#pragma unroll
        for (int mi = 0; mi < 2; ++mi)
#pragma unroll
            for (int ni = 0; ni < 2; ++ni)
                acc[mi][ni] = __builtin_amdgcn_mfma_f32_16x16x32_bf16(af[mi], bfr[ni], acc[mi][ni], 0, 0, 0);
        __syncthreads();
    }

#pragma unroll
    for (int mi = 0; mi < 2; ++mi) {
        int row0 = bm * BM + wm + mi * 16 + quad * 4;
#pragma unroll
        for (int ni = 0; ni < 2; ++ni) {
            int col = wn + ni * 16 + l15;
            unsigned short* cp = C + (size_t)(col >> 5) * ((size_t)NR * 32) + (col & 31);
#pragma unroll
            for (int r = 0; r < 4; ++r) {
                int row = row0 + r;
                if (row < M) cp[(size_t)row * 32] = f2bf1(acc[mi][ni][r]);
            }
        }
    }
}

// ---------------- aggregation: XCD-pinned slices + uniform 1KB DMAs + masked tail ----------------
// Line-rate ledger (64B lines/cy/CU): R0 0.205, R2 0.13, R4 0.24 (uniform size-16 DMAs,
// pad16), R6 0.18 (mixed-size DMAs, pad4). R4's uniform issue structure achieves the best
// rate; R6's branchy mixed-size decomposition paid more in issue overhead than the line
// savings. This round: R4's structure with an EXEC-MASKED tail DMA -- `if (lane < tq*16)`
// covers exactly the pad4 tail quads (VMEM is exec-masked; vmcnt +1 iff any lane active) --
// giving pad4 line count (13.4M vs 17.2M) at R4's issue rate. 5 shuffles/node, no dynamic
// register-array indexing (tail row shfl separate). Consume branch-free (ZROW pads = 0).
// Cross-node vmcnt pipeline: N = n(j+1) + 1(store), never a full drain mid-loop.

#define AGG_ISSUE(J, B, NJ)                                                             \
    int NJ;                                                                             \
    {                                                                                   \
        const int nq4   = (end##J + 3) >> 2;     /* quads incl pad4 */                  \
        const int nfull = nq4 >> 2;              /* full 16-row DMAs (<=3) */           \
        const int tq    = nq4 & 3;               /* tail quads (0..3) */                \
        int r16[4];                                                                     \
        _Pragma("unroll")                                                               \
        for (int k = 0; k < 4; ++k)                                                     \
            r16[k] = __shfl(elv##J, ((k << 4) + (lane >> 2)) & 63);                     \
        const int rtail = __shfl(elv##J, ((nfull << 4) + (lane >> 2)) & 63);            \
        for (int k = 0; k < nfull; ++k)                                                 \
            __builtin_amdgcn_global_load_lds(                                           \
                (GASV*)(tb32 + ((unsigned)r16[k] << 4) + ((lane & 3) << 2)),            \
                (LASV*)(&ring[w][B][k << 8]), 16, 0, 0);                                \
        if (lane < (tq << 4))                                                           \
            __builtin_amdgcn_global_load_lds(                                           \
                (GASV*)(tb32 + ((unsigned)rtail << 4) + ((lane & 3) << 2)),             \
                (LASV*)(&ring[w][B][nfull << 8]), 16, 0, 0);                            \
        NJ = nfull + (tq ? 1 : 0);                                                      \
    }

#define AGG_CONSUME(J, B)                                                               \
    {                                                                                   \
        const int nq = (end##J + 3) >> 2;                                               \
        f32x2 Acc = {0.f, 0.f};                                                         \
        const unsigned int* rb = &ring[w][B][lane];                                     \
        for (int q = 0; q < nq; ++q) {                                                  \
            unsigned int v = rb[q << 6];                                                \
            Acc.x += uasf(v << 16);                                                     \
            Acc.y += uasf(v & 0xffff0000u);                                             \
        }                                                                               \
        f32x2 Bv;                                                                       \
        Bv.x = __shfl_xor(Acc.x, 16); Bv.y = __shfl_xor(Acc.y, 16); Acc += Bv;          \
        Bv.x = __shfl_xor(Acc.x, 32); Bv.y = __shfl_xor(Acc.y, 32); Acc += Bv;          \
        if (lane < 16) {                                                                \
            float iv = (end##J > 0) ? (1.0f / (float)end##J) : 0.f;                     \
            float m0 = Acc.x * iv, m1 = Acc.y * iv;                                     \
            if (ELU) {                                                                  \
                m0 = (m0 > 0.f) ? m0 : (__expf(m0) - 1.f);                              \
                m1 = (m1 > 0.f) ? m1 : (__expf(m1) - 1.f);                              \
                *(unsigned int*)&hout[(size_t)(s0 + J) * D_H1 + slice * 32 + (lane & 15) * 2] = cvtpk(m0, m1); \
            } else {                                                                    \
                f32x2 r; r.x = m0; r.y = m1;                                            \
                *(f32x2*)(fout + (size_t)(s0 + J) * D_OUT + slice * 32 + (lane & 15) * 2) = r; \
            }                                                                           \
        }                                                                               \
        __builtin_amdgcn_sched_barrier(0);                                              \
    }

template<int LOGS, bool ELU>
__global__ __launch_bounds__(256) void agg_kernel(const unsigned short* __restrict__ t,
                                                  const int* __restrict__ deg,
                                                  const unsigned short* __restrict__ sdst,
                                                  unsigned short* __restrict__ hout,
                                                  float* __restrict__ fout) {
    __shared__ __align__(16) unsigned int ring[4][2][1024];   // 32 KB (<=64 rows/slot)
    const int bi    = blockIdx.x;
    const int slice = bi & ((1 << LOGS) - 1);
    const int g     = bi >> LOGS;
    const int w     = __builtin_amdgcn_readfirstlane(threadIdx.x >> 6);
    const int lane  = threadIdx.x & 63;
    const unsigned int* tb32 = (const unsigned int*)t + (size_t)slice * ((size_t)NR * 16);

    const int s0 = g * 16 + w * 4;
    const int end0 = deg[s0 + 0], end1 = deg[s0 + 1], end2 = deg[s0 + 2], end3 = deg[s0 + 3];
    const int elv0 = sdst[(size_t)(s0 + 0) * SLOT + lane];
    const int elv1 = sdst[(size_t)(s0 + 1) * SLOT + lane];
    const int elv2 = sdst[(size_t)(s0 + 2) * SLOT + lane];
    const int elv3 = sdst[(size_t)(s0 + 3) * SLOT + lane];

    AGG_ISSUE(0, 0, n0i);
    AGG_ISSUE(1, 1, n1i); waitvm(n1i);        // node0 loads landed (n1 newest stay in flight)
    AGG_CONSUME(0, 0);                        // ends with 1 global store
    AGG_ISSUE(2, 0, n2i); waitvm(n2i + 1);    // +1: store(0) may still be outstanding
    AGG_CONSUME(1, 1);
    AGG_ISSUE(3, 1, n3i); waitvm(n3i + 1);
    AGG_CONSUME(2, 0);
    waitvm(1);                                // node3 loads done (store(2) may remain)
    AGG_CONSUME(3, 1);
}

// ---------------- launch ----------------

extern "C" void kernel_launch(void* const* d_in, const int* in_sizes, int n_in,
                              void* d_out, int out_size, void* d_ws, size_t ws_size,
                              hipStream_t stream) {
    const float* X  = (const float*)d_in[0];
    const int*   ei = (const int*)d_in[1];
    const float* W1 = (const float*)d_in[2];
    const float* W2 = (const float*)d_in[3];
    const int* src = ei;             // edge_index[0] = segment ids
    const int* dst = ei + N_EDGES;   // edge_index[1] = gathered neighbors

    char* ws = (char*)d_ws;
    size_t off = 0;
    auto alloc = [&](size_t bytes) {
        off = (off + 255) & ~(size_t)255;
        void* p = ws + off;
        off += bytes;
        return p;
    };
    int*          gcnt = (int*)alloc((size_t)NBUK * 4);
    unsigned int* gbuk = (unsigned int*)alloc((size_t)NBUK * MAXB * 4);
    unsigned short* sdst = (unsigned short*)alloc(((size_t)N_NODES * SLOT + 64) * 2);
    int*          deg  = (int*)alloc((size_t)N_NODES * 4);
    unsigned short* Bt1 = (unsigned short*)alloc((size_t)D_H1 * D_IN * 2);
    unsigned short* Bt2 = (unsigned short*)alloc((size_t)D_OUT * D_H1 * 2);
    unsigned short* t1  = (unsigned short*)alloc((size_t)8 * NR * 32 * 2);
    unsigned short* h   = (unsigned short*)alloc((size_t)N_NODES * D_H1 * 2);
    unsigned short* t2  = (unsigned short*)alloc((size_t)2 * NR * 32 * 2);

    hipMemsetAsync(gcnt, 0, (size_t)NBUK * 4, stream);

    part_kernel<<<NPB, 256, 0, stream>>>(src, dst, gcnt, gbuk);
    sort_kernel<<<NBUK, 256, 0, stream>>>(gcnt, gbuk, sdst, deg);
    convw_kernel<<<(4 * 512 * 64 + 256 * 64 + 8 * 32 + 2 * 32 + 255) / 256, 256, 0, stream>>>(
        W1, W2, Bt1, Bt2, t1, t2);

    gemm1_kernel<<<(N_NODES + 127) / 128, 512, 0, stream>>>(X, Bt1, t1);
    agg_kernel<3, true><<<(N_NODES / 16) * 8, 256, 0, stream>>>(t1, deg, sdst, h, nullptr);
    gemm2_kernel<<<(N_NODES + 63) / 64, 256, 0, stream>>>(h, Bt2, t2);
    agg_kernel<1, false><<<(N_NODES / 16) * 2, 256, 0, stream>>>(t2, deg, sdst, nullptr, (float*)d_out);
}

// Round 8
// 351.747 us; speedup vs baseline: 1.0702x; 1.0532x over previous
//
#include <hip/hip_runtime.h>
#include <hip/hip_bf16.h>
#include <stdint.h>

#define N_NODES 50000
#define N_EDGES 1600000
#define D_IN    512
#define D_H1    256   // 4 heads * 64 concat
#define D_OUT   64

#define NBUK    196   // coarse buckets: src>>8 (256 nodes each)
#define MAXB    9216  // per-bucket region capacity (mean 8163, +11 sigma)
#define EPB     4096  // edges per partition block
#define NPB     391   // ceil(N_EDGES / EPB)
#define SLOT    96    // per-node list stride (max degree ~58, padded to mult-8)

#define NR      50001 // rows incl. zero row
#define ZROW    50000 // reserved all-zero row index (pad target)

typedef __attribute__((ext_vector_type(8))) short  short8;   // 8 bf16 = 4 VGPRs (MFMA A/B frag)
typedef __attribute__((ext_vector_type(4))) float  f32x4;    // MFMA C/D frag
typedef __attribute__((ext_vector_type(2))) float  f32x2;
typedef __attribute__((ext_vector_type(4))) unsigned int u32x4;
typedef __attribute__((ext_vector_type(2))) unsigned int u32x2;

// address-space-qualified void for the global_load_lds builtin
typedef __attribute__((address_space(1))) void GASV;
typedef __attribute__((address_space(3))) void LASV;

static __device__ __forceinline__ unsigned short f2bf(float f) {
    union { float f; unsigned int u; } c; c.f = f;
    unsigned int u = c.u;
    return (unsigned short)((u + 0x7FFFu + ((u >> 16) & 1u)) >> 16);  // RNE
}
// HW packed convert: dst.lo = bf16(a), dst.hi = bf16(b) — 1 op replaces 6.
static __device__ __forceinline__ unsigned int cvtpk(float a, float b) {
    unsigned int r;
    asm("v_cvt_pk_bf16_f32 %0, %1, %2" : "=v"(r) : "v"(a), "v"(b));
    return r;
}
static __device__ __forceinline__ unsigned short f2bf1(float f) {
    return (unsigned short)cvtpk(f, f);
}
static __device__ __forceinline__ float uasf(unsigned int u) {
    union { unsigned int u; float f; } c; c.u = u; return c.f;
}
static __device__ __forceinline__ void glds16(const unsigned int* g, unsigned int* l) {
    __builtin_amdgcn_global_load_lds((GASV*)g, (LASV*)l, 16, 0, 0);
}

// ---------------- phase 1: partition edges into 196 coarse buckets ----------------

__global__ __launch_bounds__(256) void part_kernel(const int* __restrict__ src,
                                                   const int* __restrict__ dst,
                                                   int* __restrict__ gcnt,
                                                   unsigned int* __restrict__ gbuk) {
    __shared__ int hist[NBUK];
    __shared__ int lofs[NBUK];
    __shared__ int gbase[NBUK];
    __shared__ int sbuf[256];
    __shared__ unsigned int sorted[EPB];
    __shared__ unsigned char bid[EPB];

    const int t  = threadIdx.x;
    const int e0 = blockIdx.x * EPB;
    int ec = N_EDGES - e0; if (ec > EPB) ec = EPB;

    for (int i = t; i < NBUK; i += 256) hist[i] = 0;
    __syncthreads();

    unsigned int rec[16];
    int bb[16], idx[16];
#pragma unroll
    for (int j = 0; j < 16; ++j) {
        int i = j * 256 + t;
        if (i < ec) {
            int s = src[e0 + i], d = dst[e0 + i];
            int b = s >> 8;
            rec[j] = ((unsigned int)(s & 255) << 16) | (unsigned int)d;
            bb[j]  = b;
            idx[j] = atomicAdd(&hist[b], 1);
        } else bb[j] = -1;
    }
    __syncthreads();

    int v = (t < NBUK) ? hist[t] : 0;
    sbuf[t] = v;
    __syncthreads();
#pragma unroll
    for (int off = 1; off < 256; off <<= 1) {
        int x = (t >= off) ? sbuf[t - off] : 0;
        __syncthreads();
        sbuf[t] += x;
        __syncthreads();
    }
    if (t < NBUK) {
        lofs[t]  = sbuf[t] - v;
        gbase[t] = atomicAdd(&gcnt[t], v);
    }
    __syncthreads();

#pragma unroll
    for (int j = 0; j < 16; ++j) {
        if (bb[j] >= 0) {
            int p = lofs[bb[j]] + idx[j];
            sorted[p] = rec[j];
            bid[p] = (unsigned char)bb[j];
        }
    }
    __syncthreads();

    for (int i = t; i < ec; i += 256) {
        int b = bid[i];
        int p = gbase[b] + (i - lofs[b]);
        gbuk[(size_t)b * MAXB + p] = sorted[i];
    }
}

// ---------------- phase 2: per-bucket LDS counting sort -> per-node padded lists ----------------

__global__ __launch_bounds__(256) void sort_kernel(const int* __restrict__ gcnt,
                                                   const unsigned int* __restrict__ gbuk,
                                                   unsigned short* __restrict__ sdst,
                                                   int* __restrict__ deg) {
    __shared__ int hist[256];
    __shared__ int nofs[256];
    __shared__ int sbuf[256];
    __shared__ unsigned short list[MAXB];

    const int t = threadIdx.x;
    const int b = blockIdx.x;
    const int cnt = gcnt[b];
    const unsigned int* buk = gbuk + (size_t)b * MAXB;

    hist[t] = 0;
    __syncthreads();
    for (int i = t; i < cnt; i += 256)
        atomicAdd(&hist[buk[i] >> 16], 1);
    __syncthreads();

    int v = hist[t];
    sbuf[t] = v;
    __syncthreads();
#pragma unroll
    for (int off = 1; off < 256; off <<= 1) {
        int x = (t >= off) ? sbuf[t - off] : 0;
        __syncthreads();
        sbuf[t] += x;
        __syncthreads();
    }
    nofs[t] = sbuf[t] - v;
    const int n = b * 256 + t;
    if (n < N_NODES) deg[n] = v;
    __syncthreads();

    for (int i = t; i < cnt; i += 256) {
        unsigned int r = buk[i];
        int p = atomicAdd(&nofs[r >> 16], 1);
        list[p] = (unsigned short)(r & 0xffffu);
    }
    __syncthreads();

    // cooperative coalesced writeout: 8 lanes per node, pad to mult-8 with ZROW
    for (int base = 0; base < 256; base += 32) {
        int node = base + (t >> 3);
        int l8   = t & 7;
        int vv   = hist[node];
        int beg  = nofs[node] - vv;
        int n2   = b * 256 + node;
        if (n2 < N_NODES) {
            int words = ((vv + 7) & ~7) >> 1;
            unsigned int* out32 = (unsigned int*)(sdst + (size_t)n2 * SLOT);
            for (int j2 = l8; j2 < words; j2 += 8) {
                unsigned int lo = (2 * j2     < vv) ? list[beg + 2 * j2]     : (unsigned int)ZROW;
                unsigned int hi = (2 * j2 + 1 < vv) ? list[beg + 2 * j2 + 1] : (unsigned int)ZROW;
                out32[j2] = lo | (hi << 16);
            }
        }
    }
}

// ---------------- weight repack + zero-row init ----------------

__global__ void convw_kernel(const float* __restrict__ W1, const float* __restrict__ W2,
                             unsigned short* __restrict__ Bt1, unsigned short* __restrict__ Bt2,
                             unsigned short* __restrict__ t1, unsigned short* __restrict__ t2) {
    int i = blockIdx.x * 256 + threadIdx.x;
    if (i < 4 * 512 * 64) {                 // W1[h][k][j] -> Bt1[(h*64+j)][k]
        int h = i >> 15;
        int k = (i >> 6) & 511;
        int j = i & 63;
        Bt1[(h * 64 + j) * 512 + k] = f2bf(W1[i]);
    } else if (i < 4 * 512 * 64 + 256 * 64) {
        int r = i - 4 * 512 * 64;           // W2[k][n] -> Bt2[n][k]
        int k = r >> 6;
        int n = r & 63;
        Bt2[n * 256 + k] = f2bf(W2[r]);
    } else {
        int r = i - (4 * 512 * 64 + 256 * 64);
        if (r < 256) {                      // zero row of t1
            t1[(size_t)ZROW * 256 + r] = 0;
        } else if (r < 256 + 64) {          // zero row of t2
            t2[(size_t)ZROW * 64 + (r - 256)] = 0;
        }
    }
}

// ---------------- GEMM1: t1[NR][256] = X[M][512] @ Bt1[256][512]^T (row-major out) ----------------
// BM=128, BN=256 (A read once), block=512 (8 waves 2x4), wave tile 64x64, BK=32.

__global__ __launch_bounds__(512) void gemm1_kernel(const float* __restrict__ A,
                                                    const unsigned short* __restrict__ Bt,
                                                    unsigned short* __restrict__ C) {
    constexpr int BM = 128, BK = 32, LDK = 40, K = D_IN, M = N_NODES;
    __shared__ unsigned short As[BM * LDK];   // 10.0 KB
    __shared__ unsigned short Bs[256 * LDK];  // 20.0 KB

    const int tid  = threadIdx.x;
    const int lane = tid & 63;
    const int w    = tid >> 6;
    const int wm   = (w >> 2) * 64;
    const int wn   = (w & 3) * 64;
    const int quad = lane >> 4;
    const int l15  = lane & 15;
    const int bm   = blockIdx.x;

    f32x4 acc[4][4];
#pragma unroll
    for (int mi = 0; mi < 4; ++mi)
#pragma unroll
        for (int ni = 0; ni < 4; ++ni)
            acc[mi][ni] = (f32x4){0.f, 0.f, 0.f, 0.f};

    const int r0 = tid >> 2;
    const int f8 = tid & 3;

    for (int k0 = 0; k0 < K; k0 += BK) {
        {   // stage A (128 x 32 fp32 -> bf16), HW pack-convert
            int grow = bm * BM + r0;
            if (grow >= M) grow = M - 1;
            const float* ap = A + (size_t)grow * K + k0 + f8 * 8;
            f32x4 v0 = *(const f32x4*)ap;
            f32x4 v1 = *(const f32x4*)(ap + 4);
            u32x4 pk;
            pk[0] = cvtpk(v0[0], v0[1]);
            pk[1] = cvtpk(v0[2], v0[3]);
            pk[2] = cvtpk(v1[0], v1[1]);
            pk[3] = cvtpk(v1[2], v1[3]);
            *(u32x4*)&As[r0 * LDK + f8 * 8] = pk;
        }
        {   // stage B (256 x 32 bf16)
#pragma unroll
            for (int p = 0; p < 2; ++p) {
                int row = p * 128 + r0;
                u32x4 v = *(const u32x4*)(Bt + (size_t)row * K + k0 + f8 * 8);
                *(u32x4*)&Bs[row * LDK + f8 * 8] = v;
            }
        }
        __syncthreads();

        short8 af[4], bfr[4];
#pragma unroll
        for (int mi = 0; mi < 4; ++mi)
            af[mi] = *(const short8*)&As[(wm + mi * 16 + l15) * LDK + quad * 8];
#pragma unroll
        for (int ni = 0; ni < 4; ++ni)
            bfr[ni] = *(const short8*)&Bs[(wn + ni * 16 + l15) * LDK + quad * 8];
#pragma unroll
        for (int mi = 0; mi < 4; ++mi)
#pragma unroll
            for (int ni = 0; ni < 4; ++ni)
                acc[mi][ni] = __builtin_amdgcn_mfma_f32_16x16x32_bf16(af[mi], bfr[ni], acc[mi][ni], 0, 0, 0);
        __syncthreads();
    }

    // epilogue: row-major store t1[row][col]
#pragma unroll
    for (int mi = 0; mi < 4; ++mi) {
        int row0 = bm * BM + wm + mi * 16 + quad * 4;
#pragma unroll
        for (int ni = 0; ni < 4; ++ni) {
            int col = wn + ni * 16 + l15;
#pragma unroll
            for (int r = 0; r < 4; ++r) {
                int row = row0 + r;
                if (row < M) C[(size_t)row * 256 + col] = f2bf1(acc[mi][ni][r]);
            }
        }
    }
}

// ---------------- aggF: fused agg1 + gemm2 (full-row contiguous DMA gather) ----------------
// The scattered-64B gather is pinned at ~0.2 lines/cy/CU across 5 structures (R0-R7),
// while GEMM staging via the same global_load_lds sustains 2-5x that with CONTIGUOUS
// lines. This kernel gathers full 512B t1 rows: each size-16 DMA = 2 rows = 2x8
// contiguous lines. Lane l owns cols 4l..4l+3 across all rows -> zero-shuffle reduce.
// Chunks of 4 DMAs (8 rows) double-buffered with vmcnt(4). Lists padded to mult-8.
// After the gather, the block's 16 h-rows sit in LDS -> gemm2 (h @ Bt2^T) fused as
// 8 MFMAs per wave; h never touches global memory.

__global__ __launch_bounds__(256) void aggf_kernel(const unsigned short* __restrict__ t1,
                                                   const int* __restrict__ deg,
                                                   const unsigned short* __restrict__ sdst,
                                                   const unsigned short* __restrict__ Bt2,
                                                   unsigned short* __restrict__ t2) {
    __shared__ __align__(16) unsigned int ring[4][2][1024];   // 4 waves x 2 bufs x 4KB = 32KB
    __shared__ __align__(16) unsigned short h_lds[16][264];   // 528B rows (bank-spread), 8.25KB

    const int w    = __builtin_amdgcn_readfirstlane(threadIdx.x >> 6);
    const int lane = threadIdx.x & 63;
    const int s0b  = blockIdx.x * 16;
    const int s0   = s0b + w * 4;
    const unsigned int* tb32 = (const unsigned int*)t1;
    const unsigned int loff = ((unsigned)(lane & 31)) << 2;   // 16B chunk within a row

    const int end0 = deg[s0 + 0], end1 = deg[s0 + 1], end2 = deg[s0 + 2], end3 = deg[s0 + 3];
    const int elv0 = sdst[(size_t)(s0 + 0) * SLOT + lane];
    const int elv1 = sdst[(size_t)(s0 + 1) * SLOT + lane];
    const int elv2 = sdst[(size_t)(s0 + 2) * SLOT + lane];
    const int elv3 = sdst[(size_t)(s0 + 3) * SLOT + lane];
    // force all prologue loads to complete here so compiler waits don't drain DMA counts
    asm volatile("" :: "v"(end0), "v"(end1), "v"(end2), "v"(end3),
                       "v"(elv0), "v"(elv1), "v"(elv2), "v"(elv3));

#define AGGF_ISSUE(ELV, C, B)                                                           \
    {                                                                                   \
        int q  = ((C) << 3) + (lane >> 5);                                              \
        int ra = __shfl(ELV, q);                                                        \
        int rb_ = __shfl(ELV, q + 2);                                                   \
        int rc = __shfl(ELV, q + 4);                                                    \
        int rd = __shfl(ELV, q + 6);                                                    \
        unsigned int* dp = &ring[w][B][0];                                              \
        glds16(tb32 + (unsigned)ra  * 128u + loff, dp);                                 \
        glds16(tb32 + (unsigned)rb_ * 128u + loff, dp + 256);                           \
        glds16(tb32 + (unsigned)rc  * 128u + loff, dp + 512);                           \
        glds16(tb32 + (unsigned)rd  * 128u + loff, dp + 768);                           \
    }

#define AGGF_CONSUME(B)                                                                 \
    {                                                                                   \
        const unsigned int* rbp = &ring[w][B][lane << 1];                               \
        _Pragma("unroll")                                                               \
        for (int r = 0; r < 8; ++r) {                                                   \
            u32x2 v = *(const u32x2*)(rbp + (r << 7));                                  \
            a0 += uasf(v[0] << 16); a1 += uasf(v[0] & 0xffff0000u);                     \
            a2 += uasf(v[1] << 16); a3 += uasf(v[1] & 0xffff0000u);                     \
        }                                                                               \
    }

#define AGGF_NODE(J)                                                                    \
    {                                                                                   \
        const int end = end##J;                                                         \
        const int nch = ((end + 7) & ~7) >> 3;                                          \
        float a0 = 0.f, a1 = 0.f, a2 = 0.f, a3 = 0.f;                                   \
        if (nch > 0) {                                                                  \
            AGGF_ISSUE(elv##J, 0, 0);                                                   \
            for (int c = 1; c < nch; ++c) {                                             \
                AGGF_ISSUE(elv##J, c, c & 1);                                           \
                asm volatile("s_waitcnt vmcnt(4)" ::: "memory");                        \
                __builtin_amdgcn_sched_barrier(0);                                      \
                AGGF_CONSUME((c - 1) & 1);                                              \
            }                                                                           \
            asm volatile("s_waitcnt vmcnt(0)" ::: "memory");                            \
            __builtin_amdgcn_sched_barrier(0);                                          \
            AGGF_CONSUME((nch - 1) & 1);                                                \
        }                                                                               \
        float iv = (end > 0) ? (1.0f / (float)end) : 0.f;                               \
        float m0 = a0 * iv, m1 = a1 * iv, m2 = a2 * iv, m3 = a3 * iv;                   \
        m0 = (m0 > 0.f) ? m0 : (__expf(m0) - 1.f);                                      \
        m1 = (m1 > 0.f) ? m1 : (__expf(m1) - 1.f);                                      \
        m2 = (m2 > 0.f) ? m2 : (__expf(m2) - 1.f);                                      \
        m3 = (m3 > 0.f) ? m3 : (__expf(m3) - 1.f);                                      \
        u32x2 hw;                                                                       \
        hw[0] = cvtpk(m0, m1);                                                          \
        hw[1] = cvtpk(m2, m3);                                                          \
        *(u32x2*)&h_lds[(w << 2) + J][lane << 2] = hw;                                  \
    }

    AGGF_NODE(0);
    AGGF_NODE(1);
    AGGF_NODE(2);
    AGGF_NODE(3);

    __syncthreads();

    // fused gemm2: t2[16 nodes][64] = h[16][256] @ Bt2[64][256]^T ; wave w owns 16 cols
    {
        const int l15 = lane & 15, quad = lane >> 4;
        f32x4 acc = (f32x4){0.f, 0.f, 0.f, 0.f};
#pragma unroll
        for (int st = 0; st < 8; ++st) {
            short8 afr = *(const short8*)&h_lds[l15][st * 32 + quad * 8];
            short8 bfr = *(const short8*)(Bt2 + (size_t)(w * 16 + l15) * 256 + st * 32 + quad * 8);
            acc = __builtin_amdgcn_mfma_f32_16x16x32_bf16(afr, bfr, acc, 0, 0, 0);
        }
#pragma unroll
        for (int r = 0; r < 4; ++r)
            t2[(size_t)(s0b + quad * 4 + r) * 64 + w * 16 + l15] = f2bf1(acc[r]);
    }
}

// ---------------- agg2: full-row contiguous DMA gather over t2 (128B rows) ----------------

__global__ __launch_bounds__(256) void agg2_kernel(const unsigned short* __restrict__ t2,
                                                   const int* __restrict__ deg,
                                                   const unsigned short* __restrict__ sdst,
                                                   float* __restrict__ out) {
    __shared__ __align__(16) unsigned int ring[4][2][256];    // 4 waves x 2 bufs x 1KB = 8KB

    const int w    = __builtin_amdgcn_readfirstlane(threadIdx.x >> 6);
    const int lane = threadIdx.x & 63;
    const int s0   = blockIdx.x * 16 + w * 4;
    const unsigned int* tb32 = (const unsigned int*)t2;
    const unsigned int loff = ((unsigned)(lane & 7)) << 2;    // 16B chunk within a 128B row

    const int end0 = deg[s0 + 0], end1 = deg[s0 + 1], end2 = deg[s0 + 2], end3 = deg[s0 + 3];
    const int elv0 = sdst[(size_t)(s0 + 0) * SLOT + lane];
    const int elv1 = sdst[(size_t)(s0 + 1) * SLOT + lane];
    const int elv2 = sdst[(size_t)(s0 + 2) * SLOT + lane];
    const int elv3 = sdst[(size_t)(s0 + 3) * SLOT + lane];
    asm volatile("" :: "v"(end0), "v"(end1), "v"(end2), "v"(end3),
                       "v"(elv0), "v"(elv1), "v"(elv2), "v"(elv3));

#define AGG2_ISSUE(ELV, D, B)                                                           \
    {                                                                                   \
        int r = __shfl(ELV, ((D) << 3) + (lane >> 3));                                  \
        glds16(tb32 + (unsigned)r * 32u + loff, &ring[w][B][0]);                        \
    }

#define AGG2_CONSUME(B)                                                                 \
    {                                                                                   \
        const unsigned int* rbp = &ring[w][B][lane & 31];                               \
        _Pragma("unroll")                                                               \
        for (int i = 0; i < 4; ++i) {                                                   \
            unsigned int v = rbp[(((i << 1) + (lane >> 5)) << 5)];                      \
            a0 += uasf(v << 16); a1 += uasf(v & 0xffff0000u);                           \
        }                                                                               \
    }

#define AGG2_NODE(J)                                                                    \
    {                                                                                   \
        const int end = end##J;                                                         \
        const int nch = ((end + 7) & ~7) >> 3;                                          \
        float a0 = 0.f, a1 = 0.f;                                                       \
        if (nch > 0) {                                                                  \
            AGG2_ISSUE(elv##J, 0, 0);                                                   \
            for (int d = 1; d < nch; ++d) {                                             \
                AGG2_ISSUE(elv##J, d, d & 1);                                           \
                asm volatile("s_waitcnt vmcnt(1)" ::: "memory");                        \
                __builtin_amdgcn_sched_barrier(0);                                      \
                AGG2_CONSUME((d - 1) & 1);                                              \
            }                                                                           \
            asm volatile("s_waitcnt vmcnt(0)" ::: "memory");                            \
            __builtin_amdgcn_sched_barrier(0);                                          \
            AGG2_CONSUME((nch - 1) & 1);                                                \
        }                                                                               \
        a0 += __shfl_xor(a0, 32);                                                       \
        a1 += __shfl_xor(a1, 32);                                                       \
        if (lane < 32) {                                                                \
            float iv = (end > 0) ? (1.0f / (float)end) : 0.f;                           \
            f32x2 rr; rr.x = a0 * iv; rr.y = a1 * iv;                                   \
            *(f32x2*)(out + (size_t)(s0 + J) * D_OUT + (lane & 31) * 2) = rr;           \
        }                                                                               \
    }

    AGG2_NODE(0);
    AGG2_NODE(1);
    AGG2_NODE(2);
    AGG2_NODE(3);
}

// ---------------- launch ----------------

extern "C" void kernel_launch(void* const* d_in, const int* in_sizes, int n_in,
                              void* d_out, int out_size, void* d_ws, size_t ws_size,
                              hipStream_t stream) {
    const float* X  = (const float*)d_in[0];
    const int*   ei = (const int*)d_in[1];
    const float* W1 = (const float*)d_in[2];
    const float* W2 = (const float*)d_in[3];
    const int* src = ei;             // edge_index[0] = segment ids
    const int* dst = ei + N_EDGES;   // edge_index[1] = gathered neighbors

    char* ws = (char*)d_ws;
    size_t off = 0;
    auto alloc = [&](size_t bytes) {
        off = (off + 255) & ~(size_t)255;
        void* p = ws + off;
        off += bytes;
        return p;
    };
    int*          gcnt = (int*)alloc((size_t)NBUK * 4);
    unsigned int* gbuk = (unsigned int*)alloc((size_t)NBUK * MAXB * 4);
    unsigned short* sdst = (unsigned short*)alloc(((size_t)N_NODES * SLOT + 64) * 2);
    int*          deg  = (int*)alloc((size_t)N_NODES * 4);
    unsigned short* Bt1 = (unsigned short*)alloc((size_t)D_H1 * D_IN * 2);
    unsigned short* Bt2 = (unsigned short*)alloc((size_t)D_OUT * D_H1 * 2);
    unsigned short* t1  = (unsigned short*)alloc((size_t)NR * D_H1 * 2);
    unsigned short* t2  = (unsigned short*)alloc((size_t)NR * D_OUT * 2);

    hipMemsetAsync(gcnt, 0, (size_t)NBUK * 4, stream);

    part_kernel<<<NPB, 256, 0, stream>>>(src, dst, gcnt, gbuk);
    sort_kernel<<<NBUK, 256, 0, stream>>>(gcnt, gbuk, sdst, deg);
    convw_kernel<<<(4 * 512 * 64 + 256 * 64 + 256 + 64 + 255) / 256, 256, 0, stream>>>(
        W1, W2, Bt1, Bt2, t1, t2);

    gemm1_kernel<<<(N_NODES + 127) / 128, 512, 0, stream>>>(X, Bt1, t1);
    aggf_kernel<<<N_NODES / 16, 256, 0, stream>>>(t1, deg, sdst, Bt2, t2);
    agg2_kernel<<<N_NODES / 16, 256, 0, stream>>>(t2, deg, sdst, (float*)d_out);
}